// Round 4
// baseline (234.351 us; speedup 1.0000x reference)
//
#include <hip/hip_runtime.h>
#include <hip/hip_bf16.h>

typedef __attribute__((ext_vector_type(4))) float f32x4;
typedef __attribute__((ext_vector_type(8))) short bf16x8;
typedef __attribute__((ext_vector_type(4))) float float4v;
typedef __attribute__((ext_vector_type(4))) int int4v;

#define LCH 4        // timesteps emitted per chunk
#define WARM 3       // warmup steps (contraction ~0.009/step -> ~7e-7 residual)
#define NSTEP (WARM + LCH)
#define ROWS 32      // chunk-rows per WG -> 64 KB A-panel LDS -> 2 WG/CU

// ---------------------------------------------------------------------------
// prep_Pt: P transposed + tiled for coalesced MFMA B-fragment loads.
// Pt[(nt*32+kc)*512 + nw*32 + kw] = exp(trans[(kc*32+kw)*1024 + nt*16+nw])
// ---------------------------------------------------------------------------
__global__ void prep_Pt(const float* __restrict__ trans,
                        __hip_bfloat16* __restrict__ Pt) {
  __shared__ float l[4 * 544];
  const int nt = blockIdx.x >> 3;
  const int kc0 = (blockIdx.x & 7) << 2;
  for (int e = threadIdx.x; e < 2048; e += 256) {
    const int kcl = e >> 9, kw = (e >> 4) & 31, nw = e & 15;
    l[kcl * 544 + kw * 17 + nw] =
        __expf(trans[(size_t)((kc0 + kcl) * 32 + kw) * 1024 + nt * 16 + nw]);
  }
  __syncthreads();
  for (int o = threadIdx.x; o < 2048; o += 256) {
    const int kw = o & 31, nw = (o >> 5) & 15, kcl = o >> 9;
    Pt[(size_t)(nt * 32 + kc0 + kcl) * 512 + nw * 32 + kw] =
        __float2bfloat16(l[kcl * 544 + kw * 17 + nw]);
  }
}

// ---------------------------------------------------------------------------
// CSR of xs: count (hist) -> offsets (scan) -> tlist (fill, consumes count).
// ---------------------------------------------------------------------------
__global__ void k_hist(const int* __restrict__ xs, int* __restrict__ count, int T) {
  const int t = blockIdx.x * 256 + threadIdx.x;
  if (t < T) atomicAdd(&count[xs[t]], 1);
}

__global__ __launch_bounds__(1024) void k_scan(const int* __restrict__ count,
                                               int* __restrict__ offsets) {
  __shared__ int part[1024];
  const int tid = threadIdx.x;
  const int base = tid * 32;
  int s = 0;
#pragma unroll 1
  for (int i = 0; i < 32; ++i) s += count[base + i];
  part[tid] = s;
  __syncthreads();
  for (int d = 1; d < 1024; d <<= 1) {
    const int v = (tid >= d) ? part[tid - d] : 0;
    __syncthreads();
    part[tid] += v;
    __syncthreads();
  }
  int run = part[tid] - s;  // exclusive prefix
#pragma unroll 1
  for (int i = 0; i < 32; ++i) {
    offsets[base + i] = run;
    run += count[base + i];
  }
}

__global__ void k_fill(const int* __restrict__ xs, int* __restrict__ count,
                       const int* __restrict__ offsets, int* __restrict__ tlist,
                       int T) {
  const int t = blockIdx.x * 256 + threadIdx.x;
  if (t < T) {
    const int v = xs[t];
    const int pos = atomicSub(&count[v], 1) - 1;
    tlist[offsets[v] + pos] = t;
  }
}

// ---------------------------------------------------------------------------
// k_scatter: stream emit coalesced (float4/thread); for each element with
// occurrences in xs, write bf16(exp(val)) to Ex[t][1024 + j] directly.
// Emit fetched at most once (lines with no hits skipped). Kills the 75us
// gather + transpose.
// ---------------------------------------------------------------------------
__global__ __launch_bounds__(256) void k_scatter(
    const float* __restrict__ emit, const int* __restrict__ offsets,
    const int* __restrict__ tlist, __hip_bfloat16* __restrict__ Ex, int V) {
  const int v4 = blockIdx.x * 256 + threadIdx.x;
  if (v4 >= (V >> 2)) return;
  const int j = blockIdx.y;
  const int v = v4 << 2;
  const int4v offs = *(const int4v*)&offsets[v];
  const int end = offsets[v + 4];
  if (end > offs[0]) {
    const float4v vals = *(const float4v*)&emit[(size_t)j * V + v];
#pragma unroll
    for (int e = 0; e < 4; ++e) {
      const int b = offs[e];
      const int en = (e < 3) ? offs[e + 1] : end;
      for (int k = b; k < en; ++k) {
        const int t = tlist[k];
        Ex[(size_t)t * 1024 + j] = __float2bfloat16(__expf(vals[e]));
      }
    }
  }
}

// ---------------------------------------------------------------------------
// prep_A0: row 0 = exact alpha_0 = exp(start)*E_0; rows>=1 = 1.0
// ---------------------------------------------------------------------------
__global__ void prep_A0(const float* __restrict__ start,
                        const __hip_bfloat16* __restrict__ Ex,
                        __hip_bfloat16* __restrict__ A0) {
  const int idx = blockIdx.x * 256 + threadIdx.x;
  const int r = idx >> 10, j = idx & 1023;
  const float v = (r == 0) ? __expf(start[j]) * __bfloat162float(Ex[j]) : 1.0f;
  A0[idx] = __float2bfloat16(v);
}

__device__ __forceinline__ void gload_lds16(const void* g, void* l) {
  __builtin_amdgcn_global_load_lds((const __attribute__((address_space(1))) void*)g,
                                   (__attribute__((address_space(3))) void*)l,
                                   16, 0, 0);
}

// ---------------------------------------------------------------------------
// one recurrence step:  A_next = (A_cur @ P) .* E  * 2^15
// grid (16 ng, 32 mg) = 512 WGs -> 2 WG/CU (64.5 KB LDS), 4 waves each.
// WG tile: 32 rows x 64 cols; wave w -> col-tile ntw = ng*4+w.
// A panel staged once in MFMA-fragment order via global_load_lds (linear
// lane order -> conflict-free ds_read_b128); 32 B-frags in 128 VGPRs.
// One barrier, then 64 {ds_read_b128 + MFMA} per wave.
// ---------------------------------------------------------------------------
__global__ __launch_bounds__(256, 2) void hmm_step(
    const __hip_bfloat16* __restrict__ Acur, __hip_bfloat16* __restrict__ Anext,
    const __hip_bfloat16* __restrict__ Pt, const __hip_bfloat16* __restrict__ Ex,
    float* __restrict__ Spart, int s) {
  __shared__ __align__(16) __hip_bfloat16 Albs[64 * 512];  // 64 KB
  __shared__ float sred[4][ROWS];
  const int tid = threadIdx.x;
  const int w = tid >> 6;
  const int l = tid & 63;
  const int ng = blockIdx.x;
  const int mg = blockIdx.y;
  const int m0 = mg << 5;
  const int n0 = ng << 6;
  const int ntw = (ng << 2) + w;

  // A stage in fragment order: chunk c=(kc*2+rt); lane l stages its own frag.
#pragma unroll
  for (int i = 0; i < 16; ++i) {
    const int c = (w << 4) + i;
    const int kc = c >> 1, rt = c & 1;
    const __hip_bfloat16* gp = Acur + (size_t)(m0 + rt * 16 + (l & 15)) * 1024 +
                               kc * 32 + (l >> 4) * 8;
    gload_lds16(gp, Albs + (size_t)c * 512);
  }

  // B-frag preload: 32 x bf16x8 = 128 VGPRs (this wave's 16-col panel, all k)
  bf16x8 bf[32];
  const __hip_bfloat16* bbase =
      Pt + (size_t)ntw * 32 * 512 + (l & 15) * 32 + (l >> 4) * 8;
#pragma unroll
  for (int kc = 0; kc < 32; ++kc) bf[kc] = *(const bf16x8*)(bbase + kc * 512);

  f32x4 acc[2];
#pragma unroll
  for (int rt = 0; rt < 2; ++rt)
#pragma unroll
    for (int jj = 0; jj < 4; ++jj) acc[rt][jj] = 0.0f;

  __syncthreads();

#pragma unroll
  for (int kc = 0; kc < 32; ++kc) {
#pragma unroll
    for (int rt = 0; rt < 2; ++rt) {
      const bf16x8 af = *(const bf16x8*)(Albs + (kc * 2 + rt) * 512 + l * 8);
      acc[rt] = __builtin_amdgcn_mfma_f32_16x16x32_bf16(af, bf[kc], acc[rt], 0, 0, 0);
    }
  }

  // epilogue: emission scale, 2^15 rescale, bf16 writeback, row partial sums
  const int n = n0 + (w << 4) + (l & 15);
#pragma unroll
  for (int rt = 0; rt < 2; ++rt) {
#pragma unroll
    for (int j = 0; j < 4; ++j) {
      const int rl = rt * 16 + ((l >> 4) << 2) + j;
      const int r = m0 + rl;
      int t = (r == 0) ? (s - WARM) : (r * LCH - 1 - WARM + s);
      if (t < 0) t = 0;
      float outv;
      if ((r > 0) || (s > WARM))
        outv = acc[rt][j] * __bfloat162float(Ex[(size_t)t * 1024 + n]) * 32768.0f;
      else
        outv = __bfloat162float(Acur[n]);  // chunk 0 frozen during warmup
      Anext[(size_t)r * 1024 + n] = __float2bfloat16(outv);
      float ssum = outv;
      ssum += __shfl_xor(ssum, 1);
      ssum += __shfl_xor(ssum, 2);
      ssum += __shfl_xor(ssum, 4);
      ssum += __shfl_xor(ssum, 8);
      if ((l & 15) == 0) sred[w][rl] = ssum;
    }
  }
  __syncthreads();
  if (s >= WARM && tid < ROWS) {
    const float tot = sred[0][tid] + sred[1][tid] + sred[2][tid] + sred[3][tid];
    Spart[((size_t)(m0 + tid) * (LCH + 1) + (s - WARM)) * 16 + ng] = tot;
  }
}

// ---------------------------------------------------------------------------
// final: Z_t from log-ratios of consecutive scaled sums.
// ---------------------------------------------------------------------------
__global__ void hmm_final(const float* __restrict__ Spart, float* __restrict__ out,
                          int T) {
  const int t = blockIdx.x * 256 + threadIdx.x;
  if (t >= T) return;
  const float C15 = 10.397207708399179f;  // 15*ln2
  auto S = [&](int c, int k) {
    const float* p = Spart + ((size_t)c * (LCH + 1) + k) * 16;
    float acc = 0.f;
#pragma unroll
    for (int g = 0; g < 16; ++g) acc += p[g];
    return acc;
  };
  float z;
  if (t == 0)
    z = logf(S(0, 0));
  else if (t < LCH)
    z = logf(S(0, t)) - logf(S(0, t - 1)) - C15;
  else {
    const int c = t >> 2, e = t & 3;
    z = logf(S(c, e + 1)) - logf(S(c, e)) - C15;
  }
  out[t] = z;
}

// ---------------------------------------------------------------------------
extern "C" void kernel_launch(void* const* d_in, const int* in_sizes, int n_in,
                              void* d_out, int out_size, void* d_ws, size_t ws_size,
                              hipStream_t stream) {
  const int* xs = (const int*)d_in[0];
  const float* start = (const float*)d_in[1];
  const float* trans = (const float*)d_in[2];
  const float* emit = (const float*)d_in[3];
  float* out = (float*)d_out;
  const int T = out_size;            // 4096
  const int K = in_sizes[1];         // 1024
  const int V = in_sizes[3] / K;     // 32000
  const int C = T / LCH;             // 1024 chunks

  char* ws = (char*)d_ws;
  __hip_bfloat16* Pt = (__hip_bfloat16*)ws;                   // 2 MB @ 0
  __hip_bfloat16* Ex = (__hip_bfloat16*)(ws + (2u << 20));    // 8 MB @ 2
  __hip_bfloat16* A0 = (__hip_bfloat16*)(ws + (10u << 20));   // 2 MB @ 10
  __hip_bfloat16* A1 = (__hip_bfloat16*)(ws + (12u << 20));   // 2 MB @ 12
  float* Spart       = (float*)(ws + (14u << 20));            // 320 KB @ 14
  int* count         = (int*)(ws + (15u << 20));              // 128 KB @ 15
  int* offsets       = (int*)(ws + (15u << 20) + (128u << 10));  // 128 KB
  int* tlist         = (int*)(ws + (15u << 20) + (256u << 10));  // 16 KB

  hipMemsetAsync(count, 0, 32768 * sizeof(int), stream);
  k_hist<<<dim3((T + 255) / 256), dim3(256), 0, stream>>>(xs, count, T);
  k_scan<<<dim3(1), dim3(1024), 0, stream>>>(count, offsets);
  k_fill<<<dim3((T + 255) / 256), dim3(256), 0, stream>>>(xs, count, offsets, tlist, T);
  k_scatter<<<dim3((V / 4 + 255) / 256, K), dim3(256), 0, stream>>>(emit, offsets,
                                                                    tlist, Ex, V);
  prep_Pt<<<dim3(512), dim3(256), 0, stream>>>(trans, Pt);
  prep_A0<<<dim3(C * 4), dim3(256), 0, stream>>>(start, Ex, A0);
  for (int s = 1; s <= NSTEP; ++s) {
    const __hip_bfloat16* ain = (s & 1) ? A0 : A1;
    __hip_bfloat16* aout = (s & 1) ? A1 : A0;
    hmm_step<<<dim3(16, C / ROWS), dim3(256), 0, stream>>>(ain, aout, Pt, Ex, Spart, s);
  }
  hmm_final<<<dim3((T + 255) / 256), dim3(256), 0, stream>>>(Spart, out, T);
}